// Round 1
// baseline (963.726 us; speedup 1.0000x reference)
//
#include <hip/hip_runtime.h>
#include <stdint.h>
#include <math.h>

#define NUM_TOK 8192
#define DM 512
#define NE 8
#define NH 2048
#define ROW_PAD 128   // GEMM M-tiles may read up to 127 rows past the last valid row

typedef float f32x4 __attribute__((ext_vector_type(4)));
typedef __bf16 bf16x8 __attribute__((ext_vector_type(8)));

// ws layout (bytes)
#define WS_COUNTS   0
#define WS_CURSORS  32
#define WS_OFFSETS  64
#define WS_IMP      96
#define WS_EXP      128                      // int[8192]
#define WS_WTOK     (128 + 32768)            // float[8192]
#define WS_PERM     (128 + 65536)            // int[8192]
#define WS_XG       98560                    // bf16 (8192+128) x 512
#define WS_H        (98560 + 8519680)        // bf16 (8192+128) x 2048

__device__ __forceinline__ uint16_t f2bf(float f) {
  union { float f; uint32_t u; } c; c.f = f;
  return (uint16_t)((c.u + 0x7FFFu + ((c.u >> 16) & 1u)) >> 16);
}

// ---------------- router: logits (fp64), gumbel argmax, weight, counts, importance ----------------
__global__ __launch_bounds__(256) void k_router(
    const float* __restrict__ x, const float* __restrict__ u,
    const float* __restrict__ rw, const float* __restrict__ rb,
    int* __restrict__ counts, float* __restrict__ imp,
    int* __restrict__ expert_of, float* __restrict__ wtok)
{
  __shared__ float s_rw[DM * NE];
  int tid = threadIdx.x;
  for (int i = tid; i < DM * NE / 4; i += 256)
    ((float4*)s_rw)[i] = ((const float4*)rw)[i];
  __syncthreads();

  int t = blockIdx.x * 256 + tid;
  double acc[NE];
  #pragma unroll
  for (int e = 0; e < NE; ++e) acc[e] = 0.0;
  const float* xr = x + (size_t)t * DM;
  for (int d = 0; d < DM; ++d) {
    double xv = (double)xr[d];
    float4 r0 = ((const float4*)s_rw)[d * 2];
    float4 r1 = ((const float4*)s_rw)[d * 2 + 1];
    acc[0] += xv * (double)r0.x;
    acc[1] += xv * (double)r0.y;
    acc[2] += xv * (double)r0.z;
    acc[3] += xv * (double)r0.w;
    acc[4] += xv * (double)r1.x;
    acc[5] += xv * (double)r1.y;
    acc[6] += xv * (double)r1.z;
    acc[7] += xv * (double)r1.w;
  }
  double lg[NE];
  #pragma unroll
  for (int e = 0; e < NE; ++e) lg[e] = acc[e] + (double)rb[e];

  // gumbel-perturbed argmax (first max wins, matching jnp.argmax)
  double ybest = -1e300; int sel = 0;
  double y[NE];
  #pragma unroll
  for (int e = 0; e < NE; ++e) {
    double uv = (double)u[t * NE + e];
    double g = -log(-log(uv) + 1e-10);
    y[e] = lg[e] + g;
    if (y[e] > ybest) { ybest = y[e]; sel = e; }
  }
  double s = 0.0;
  #pragma unroll
  for (int e = 0; e < NE; ++e) s += exp(y[e] - ybest);
  double p = 1.0 / s;                    // y_soft at the selected expert
  float w = (float)((1.0 - p) + p);      // hard - sg(y_soft) + y_soft, selected entry

  expert_of[t] = sel;
  wtok[t] = w;
  atomicAdd(&counts[sel], 1);

  // softmax(logits) for importance (aux loss)
  double lm = lg[0];
  #pragma unroll
  for (int e = 1; e < NE; ++e) lm = fmax(lm, lg[e]);
  double ss = 0.0; double pr[NE];
  #pragma unroll
  for (int e = 0; e < NE; ++e) { pr[e] = exp(lg[e] - lm); ss += pr[e]; }
  double inv = 1.0 / ss;
  #pragma unroll
  for (int e = 0; e < NE; ++e) {
    float v = (float)(pr[e] * inv);
    #pragma unroll
    for (int off = 32; off; off >>= 1) v += __shfl_xor(v, off, 64);
    if ((tid & 63) == 0) atomicAdd(&imp[e], v);
  }
}

// ---------------- offsets (prefix sum of counts) + aux loss ----------------
__global__ void k_aux_offsets(const int* __restrict__ counts, const float* __restrict__ imp,
                              int* __restrict__ offsets, float* __restrict__ aux_out)
{
  if (threadIdx.x == 0) {
    int o = 0;
    for (int e = 0; e < NE; ++e) { offsets[e] = o; o += counts[e]; }
    float a = 0.0f;
    for (int e = 0; e < NE; ++e) {
      float dv = imp[e] / 8192.0f - 0.125f;
      a += dv * dv;
    }
    aux_out[0] = a / 8.0f;
  }
}

// ---------------- counting-sort scatter: perm[pos] = token ----------------
__global__ __launch_bounds__(256) void k_scatter(
    const int* __restrict__ expert_of, const int* __restrict__ offsets,
    int* __restrict__ cursors, int* __restrict__ perm)
{
  int t = blockIdx.x * 256 + threadIdx.x;
  int e = expert_of[t];
  int pos = offsets[e] + atomicAdd(&cursors[e], 1);
  perm[pos] = t;
}

// ---------------- gather x rows into sorted bf16 Xg ----------------
__global__ __launch_bounds__(64) void k_gather(
    const float* __restrict__ x, const int* __restrict__ perm, uint16_t* __restrict__ Xg)
{
  int r = blockIdx.x;
  int lane = threadIdx.x;
  int t = perm[r];
  const float4* src = (const float4*)(x + (size_t)t * DM);
  float4 a = src[lane * 2];
  float4 b = src[lane * 2 + 1];
  uint32_t p0 = (uint32_t)f2bf(a.x) | ((uint32_t)f2bf(a.y) << 16);
  uint32_t p1 = (uint32_t)f2bf(a.z) | ((uint32_t)f2bf(a.w) << 16);
  uint32_t p2 = (uint32_t)f2bf(b.x) | ((uint32_t)f2bf(b.y) << 16);
  uint32_t p3 = (uint32_t)f2bf(b.z) | ((uint32_t)f2bf(b.w) << 16);
  uint4 v = make_uint4(p0, p1, p2, p3);
  ((uint4*)(Xg + (size_t)r * DM))[lane] = v;
}

// ---------------- layer 1: h = gelu(Xg @ w1[e] + b1[e]), bf16 MFMA ----------------
__global__ __launch_bounds__(256) void k_ffn1(
    const uint16_t* __restrict__ Xg, const float* __restrict__ w1,
    const float* __restrict__ b1,
    const int* __restrict__ offsets, const int* __restrict__ counts,
    uint16_t* __restrict__ hbuf)
{
  int e = blockIdx.z;
  int row0 = offsets[e] + blockIdx.x * 128;
  int row_end = offsets[e] + counts[e];
  if (row0 >= row_end) return;
  int n0 = blockIdx.y * 128;
  const float* w1e = w1 + (size_t)e * DM * NH;

  __shared__ uint16_t As[128 * 72];
  __shared__ uint16_t Bs[128 * 72];

  int tid = threadIdx.x;
  int lane = tid & 63, wid = tid >> 6;
  int wm = wid >> 1, wn = wid & 1;
  int l16 = lane & 15, quad = lane >> 4;

  f32x4 acc[4][4] = {};

  for (int k0 = 0; k0 < DM; k0 += 64) {
    // stage A: Xg rows row0..row0+127, cols k0..k0+63 (bf16, 16B chunks)
    #pragma unroll
    for (int it = 0; it < 4; ++it) {
      int idx = it * 256 + tid;
      int row = idx >> 3, kc = (idx & 7) << 3;
      uint4 v = *(const uint4*)(Xg + (size_t)(row0 + row) * DM + k0 + kc);
      *(uint4*)(As + row * 72 + kc) = v;
    }
    // stage B transposed: w1e[k0+k][n0+nc..+3] -> Bs[n][k], f32->bf16
    #pragma unroll
    for (int it = 0; it < 8; ++it) {
      int idx = it * 256 + tid;
      int k = idx >> 5, nc = (idx & 31) << 2;
      float4 v = *(const float4*)(w1e + (size_t)(k0 + k) * NH + n0 + nc);
      Bs[(nc + 0) * 72 + k] = f2bf(v.x);
      Bs[(nc + 1) * 72 + k] = f2bf(v.y);
      Bs[(nc + 2) * 72 + k] = f2bf(v.z);
      Bs[(nc + 3) * 72 + k] = f2bf(v.w);
    }
    __syncthreads();
    #pragma unroll
    for (int ks = 0; ks < 2; ++ks) {
      bf16x8 a[4], b[4];
      #pragma unroll
      for (int mi = 0; mi < 4; ++mi)
        a[mi] = *(const bf16x8*)(As + (wm * 64 + mi * 16 + l16) * 72 + ks * 32 + quad * 8);
      #pragma unroll
      for (int ni = 0; ni < 4; ++ni)
        b[ni] = *(const bf16x8*)(Bs + (wn * 64 + ni * 16 + l16) * 72 + ks * 32 + quad * 8);
      #pragma unroll
      for (int mi = 0; mi < 4; ++mi)
        #pragma unroll
        for (int ni = 0; ni < 4; ++ni)
          acc[mi][ni] = __builtin_amdgcn_mfma_f32_16x16x32_bf16(a[mi], b[ni], acc[mi][ni], 0, 0, 0);
    }
    __syncthreads();
  }

  // epilogue: + b1, exact gelu, bf16 store
  #pragma unroll
  for (int ni = 0; ni < 4; ++ni) {
    int col = n0 + wn * 64 + ni * 16 + l16;
    float bv = b1[e * NH + col];
    #pragma unroll
    for (int mi = 0; mi < 4; ++mi) {
      int rbase = wm * 64 + mi * 16 + quad * 4;
      #pragma unroll
      for (int r = 0; r < 4; ++r) {
        int grow = row0 + rbase + r;
        if (grow < row_end) {
          float v = acc[mi][ni][r] + bv;
          float gl = 0.5f * v * (1.0f + erff(v * 0.70710678118654752440f));
          hbuf[(size_t)grow * NH + col] = f2bf(gl);
        }
      }
    }
  }
}

// ---------------- layer 2: out[token] = (h @ w2[e] + b2[e]) * w_token, scatter ----------------
__global__ __launch_bounds__(256) void k_ffn2(
    const uint16_t* __restrict__ hbuf, const float* __restrict__ w2,
    const float* __restrict__ b2,
    const int* __restrict__ offsets, const int* __restrict__ counts,
    const int* __restrict__ perm, const float* __restrict__ wtok,
    float* __restrict__ out)
{
  int e = blockIdx.z;
  int row0 = offsets[e] + blockIdx.x * 128;
  int row_end = offsets[e] + counts[e];
  if (row0 >= row_end) return;
  int n0 = blockIdx.y * 128;
  const float* w2e = w2 + (size_t)e * NH * DM;

  __shared__ uint16_t As[128 * 72];
  __shared__ uint16_t Bs[128 * 72];

  int tid = threadIdx.x;
  int lane = tid & 63, wid = tid >> 6;
  int wm = wid >> 1, wn = wid & 1;
  int l16 = lane & 15, quad = lane >> 4;

  f32x4 acc[4][4] = {};

  for (int k0 = 0; k0 < NH; k0 += 64) {
    #pragma unroll
    for (int it = 0; it < 4; ++it) {
      int idx = it * 256 + tid;
      int row = idx >> 3, kc = (idx & 7) << 3;
      uint4 v = *(const uint4*)(hbuf + (size_t)(row0 + row) * NH + k0 + kc);
      *(uint4*)(As + row * 72 + kc) = v;
    }
    #pragma unroll
    for (int it = 0; it < 8; ++it) {
      int idx = it * 256 + tid;
      int k = idx >> 5, nc = (idx & 31) << 2;
      float4 v = *(const float4*)(w2e + (size_t)(k0 + k) * DM + n0 + nc);
      Bs[(nc + 0) * 72 + k] = f2bf(v.x);
      Bs[(nc + 1) * 72 + k] = f2bf(v.y);
      Bs[(nc + 2) * 72 + k] = f2bf(v.z);
      Bs[(nc + 3) * 72 + k] = f2bf(v.w);
    }
    __syncthreads();
    #pragma unroll
    for (int ks = 0; ks < 2; ++ks) {
      bf16x8 a[4], b[4];
      #pragma unroll
      for (int mi = 0; mi < 4; ++mi)
        a[mi] = *(const bf16x8*)(As + (wm * 64 + mi * 16 + l16) * 72 + ks * 32 + quad * 8);
      #pragma unroll
      for (int ni = 0; ni < 4; ++ni)
        b[ni] = *(const bf16x8*)(Bs + (wn * 64 + ni * 16 + l16) * 72 + ks * 32 + quad * 8);
      #pragma unroll
      for (int mi = 0; mi < 4; ++mi)
        #pragma unroll
        for (int ni = 0; ni < 4; ++ni)
          acc[mi][ni] = __builtin_amdgcn_mfma_f32_16x16x32_bf16(a[mi], b[ni], acc[mi][ni], 0, 0, 0);
    }
    __syncthreads();
  }

  #pragma unroll
  for (int ni = 0; ni < 4; ++ni) {
    int col = n0 + wn * 64 + ni * 16 + l16;
    float bv = b2[e * DM + col];
    #pragma unroll
    for (int mi = 0; mi < 4; ++mi) {
      int rbase = wm * 64 + mi * 16 + quad * 4;
      #pragma unroll
      for (int r = 0; r < 4; ++r) {
        int grow = row0 + rbase + r;
        if (grow < row_end) {
          int tk = perm[grow];
          float wt = wtok[tk];
          out[(size_t)tk * DM + col] = (acc[mi][ni][r] + bv) * wt;
        }
      }
    }
  }
}

extern "C" void kernel_launch(void* const* d_in, const int* in_sizes, int n_in,
                              void* d_out, int out_size, void* d_ws, size_t ws_size,
                              hipStream_t stream)
{
  const float* x  = (const float*)d_in[0];
  const float* u  = (const float*)d_in[1];
  const float* rw = (const float*)d_in[2];
  const float* rb = (const float*)d_in[3];
  const float* w1 = (const float*)d_in[4];
  const float* b1 = (const float*)d_in[5];
  const float* w2 = (const float*)d_in[6];
  const float* b2 = (const float*)d_in[7];
  float* out = (float*)d_out;

  char* ws = (char*)d_ws;
  int*      counts    = (int*)(ws + WS_COUNTS);
  int*      cursors   = (int*)(ws + WS_CURSORS);
  int*      offsets   = (int*)(ws + WS_OFFSETS);
  float*    imp       = (float*)(ws + WS_IMP);
  int*      expert_of = (int*)(ws + WS_EXP);
  float*    wtok      = (float*)(ws + WS_WTOK);
  int*      perm      = (int*)(ws + WS_PERM);
  uint16_t* Xg        = (uint16_t*)(ws + WS_XG);
  uint16_t* hbuf      = (uint16_t*)(ws + WS_H);

  hipMemsetAsync(d_ws, 0, 128, stream);
  k_router<<<NUM_TOK / 256, 256, 0, stream>>>(x, u, rw, rb, counts, imp, expert_of, wtok);
  k_aux_offsets<<<1, 64, 0, stream>>>(counts, imp, offsets, out + (size_t)NUM_TOK * DM);
  k_scatter<<<NUM_TOK / 256, 256, 0, stream>>>(expert_of, offsets, cursors, perm);
  k_gather<<<NUM_TOK, 64, 0, stream>>>(x, perm, Xg);
  k_ffn1<<<dim3(64, 16, NE), 256, 0, stream>>>(Xg, w1, b1, offsets, counts, hbuf);
  k_ffn2<<<dim3(64, 4, NE), 256, 0, stream>>>(hbuf, w2, b2, offsets, counts, perm, wtok, out);
}

// Round 2
// 574.347 us; speedup vs baseline: 1.6779x; 1.6779x over previous
//
#include <hip/hip_runtime.h>
#include <stdint.h>
#include <math.h>

#define NUM_TOK 8192
#define DM 512
#define NE 8
#define NH 2048

typedef float f32x4 __attribute__((ext_vector_type(4)));
typedef __bf16 bf16x8 __attribute__((ext_vector_type(8)));

// ws layout (bytes)
#define WS_COUNTS   0
#define WS_CURSORS  32
#define WS_OFFSETS  64
#define WS_IMP      96
#define WS_EXP      128                       // int[8192]
#define WS_WTOK     (128 + 32768)             // float[8192]
#define WS_PERM     (128 + 65536)             // int[8192]
#define WS_XG       98560                     // bf16 (8192+128) x 512
#define WS_H        (98560 + 8519680)         // bf16 (8192+128) x 2048 -> ends 42,696,960
#define WS_W1T      42696960                  // bf16 [8][2048][512]  = 16 MB
#define WS_W2T      59474176                  // bf16 [8][512][2048]  = 16 MB -> ends 76,251,392

__device__ __forceinline__ uint16_t f2bf(float f) {
  union { float f; uint32_t u; } c; c.f = f;
  return (uint16_t)((c.u + 0x7FFFu + ((c.u >> 16) & 1u)) >> 16);
}

// ---------------- router: logits (fp64), gumbel argmax, weight, counts, importance ----------------
__global__ __launch_bounds__(256) void k_router(
    const float* __restrict__ x, const float* __restrict__ u,
    const float* __restrict__ rw, const float* __restrict__ rb,
    int* __restrict__ counts, float* __restrict__ imp,
    int* __restrict__ expert_of, float* __restrict__ wtok)
{
  __shared__ float s_rw[DM * NE];
  int tid = threadIdx.x;
  for (int i = tid; i < DM * NE / 4; i += 256)
    ((float4*)s_rw)[i] = ((const float4*)rw)[i];
  __syncthreads();

  int t = blockIdx.x * 256 + tid;
  double acc[NE];
  #pragma unroll
  for (int e = 0; e < NE; ++e) acc[e] = 0.0;
  const float* xr = x + (size_t)t * DM;
  for (int d = 0; d < DM; ++d) {
    double xv = (double)xr[d];
    float4 r0 = ((const float4*)s_rw)[d * 2];
    float4 r1 = ((const float4*)s_rw)[d * 2 + 1];
    acc[0] += xv * (double)r0.x;
    acc[1] += xv * (double)r0.y;
    acc[2] += xv * (double)r0.z;
    acc[3] += xv * (double)r0.w;
    acc[4] += xv * (double)r1.x;
    acc[5] += xv * (double)r1.y;
    acc[6] += xv * (double)r1.z;
    acc[7] += xv * (double)r1.w;
  }
  double lg[NE];
  #pragma unroll
  for (int e = 0; e < NE; ++e) lg[e] = acc[e] + (double)rb[e];

  // gumbel-perturbed argmax (first max wins, matching jnp.argmax)
  double ybest = -1e300; int sel = 0;
  double y[NE];
  #pragma unroll
  for (int e = 0; e < NE; ++e) {
    double uv = (double)u[t * NE + e];
    double g = -log(-log(uv) + 1e-10);
    y[e] = lg[e] + g;
    if (y[e] > ybest) { ybest = y[e]; sel = e; }
  }
  double s = 0.0;
  #pragma unroll
  for (int e = 0; e < NE; ++e) s += exp(y[e] - ybest);
  double p = 1.0 / s;                    // y_soft at the selected expert
  float w = (float)((1.0 - p) + p);      // hard - sg(y_soft) + y_soft, selected entry

  expert_of[t] = sel;
  wtok[t] = w;
  atomicAdd(&counts[sel], 1);

  // softmax(logits) for importance (aux loss)
  double lm = lg[0];
  #pragma unroll
  for (int e = 1; e < NE; ++e) lm = fmax(lm, lg[e]);
  double ss = 0.0; double pr[NE];
  #pragma unroll
  for (int e = 0; e < NE; ++e) { pr[e] = exp(lg[e] - lm); ss += pr[e]; }
  double inv = 1.0 / ss;
  #pragma unroll
  for (int e = 0; e < NE; ++e) {
    float v = (float)(pr[e] * inv);
    #pragma unroll
    for (int off = 32; off; off >>= 1) v += __shfl_xor(v, off, 64);
    if ((tid & 63) == 0) atomicAdd(&imp[e], v);
  }
}

// ---------------- offsets (prefix sum of counts) + aux loss ----------------
__global__ void k_aux_offsets(const int* __restrict__ counts, const float* __restrict__ imp,
                              int* __restrict__ offsets, float* __restrict__ aux_out)
{
  if (threadIdx.x == 0) {
    int o = 0;
    for (int e = 0; e < NE; ++e) { offsets[e] = o; o += counts[e]; }
    float a = 0.0f;
    for (int e = 0; e < NE; ++e) {
      float dv = imp[e] / 8192.0f - 0.125f;
      a += dv * dv;
    }
    aux_out[0] = a / 8.0f;
  }
}

// ---------------- counting-sort scatter: perm[pos] = token ----------------
__global__ __launch_bounds__(256) void k_scatter(
    const int* __restrict__ expert_of, const int* __restrict__ offsets,
    int* __restrict__ cursors, int* __restrict__ perm)
{
  int t = blockIdx.x * 256 + threadIdx.x;
  int e = expert_of[t];
  int pos = offsets[e] + atomicAdd(&cursors[e], 1);
  perm[pos] = t;
}

// ---------------- gather x rows into sorted bf16 Xg ----------------
__global__ __launch_bounds__(64) void k_gather(
    const float* __restrict__ x, const int* __restrict__ perm, uint16_t* __restrict__ Xg)
{
  int r = blockIdx.x;
  int lane = threadIdx.x;
  int t = perm[r];
  const float4* src = (const float4*)(x + (size_t)t * DM);
  float4 a = src[lane * 2];
  float4 b = src[lane * 2 + 1];
  uint32_t p0 = (uint32_t)f2bf(a.x) | ((uint32_t)f2bf(a.y) << 16);
  uint32_t p1 = (uint32_t)f2bf(a.z) | ((uint32_t)f2bf(a.w) << 16);
  uint32_t p2 = (uint32_t)f2bf(b.x) | ((uint32_t)f2bf(b.y) << 16);
  uint32_t p3 = (uint32_t)f2bf(b.z) | ((uint32_t)f2bf(b.w) << 16);
  uint4 v = make_uint4(p0, p1, p2, p3);
  ((uint4*)(Xg + (size_t)r * DM))[lane] = v;
}

// ---------------- weight transpose+convert: src [e][K][N] f32 -> dst [e][N][K] bf16 ----------------
// grid: (N/64, K/64, NE), 256 threads
__global__ __launch_bounds__(256) void k_transpose_bf16(
    const float* __restrict__ src, uint16_t* __restrict__ dst, int K, int N)
{
  __shared__ float T[64][65];
  int e = blockIdx.z;
  const float* s = src + (size_t)e * K * N;
  uint16_t* d = dst + (size_t)e * K * N;
  int n0 = blockIdx.x * 64, k0 = blockIdx.y * 64;
  int tid = threadIdx.x;
  int tr = tid >> 4;           // 0..15 (k row within pass)
  int tc = (tid & 15) * 4;     // 0..60 (n col chunk)
  #pragma unroll
  for (int p = 0; p < 4; ++p) {
    int k = tr + p * 16;
    float4 v = *(const float4*)(s + (size_t)(k0 + k) * N + n0 + tc);
    T[k][tc] = v.x; T[k][tc + 1] = v.y; T[k][tc + 2] = v.z; T[k][tc + 3] = v.w;
  }
  __syncthreads();
  #pragma unroll
  for (int p = 0; p < 2; ++p) {
    int slot = p * 256 + tid;
    int n = slot >> 3;          // 0..63
    int c = (slot & 7) * 8;     // k chunk of 8
    uint16_t tmp[8];
    #pragma unroll
    for (int j = 0; j < 8; ++j) tmp[j] = f2bf(T[c + j][n]);
    *(uint4*)(d + (size_t)(n0 + n) * K + k0 + c) = *(uint4*)tmp;
  }
}

// ---------------- layer 1: h = gelu(Xg @ w1t[e]^T + b1[e]), bf16 MFMA ----------------
__global__ __launch_bounds__(256) void k_ffn1(
    const uint16_t* __restrict__ Xg, const uint16_t* __restrict__ w1t,
    const float* __restrict__ b1,
    const int* __restrict__ offsets, const int* __restrict__ counts,
    uint16_t* __restrict__ hbuf)
{
  int e = blockIdx.z;
  int row0 = offsets[e] + blockIdx.x * 128;
  int row_end = offsets[e] + counts[e];
  if (row0 >= row_end) return;
  int n0 = blockIdx.y * 128;
  const uint16_t* Bt = w1t + (size_t)e * DM * NH;   // [2048][512] bf16

  __shared__ uint16_t As[128 * 72];
  __shared__ uint16_t Bs[128 * 72];

  int tid = threadIdx.x;
  int lane = tid & 63, wid = tid >> 6;
  int wm = wid >> 1, wn = wid & 1;
  int l16 = lane & 15, quad = lane >> 4;

  f32x4 acc[4][4] = {};

  for (int k0 = 0; k0 < DM; k0 += 64) {
    #pragma unroll
    for (int it = 0; it < 4; ++it) {
      int idx = it * 256 + tid;
      int row = idx >> 3, kc = (idx & 7) << 3;
      uint4 v = *(const uint4*)(Xg + (size_t)(row0 + row) * DM + k0 + kc);
      *(uint4*)(As + row * 72 + kc) = v;
    }
    #pragma unroll
    for (int it = 0; it < 4; ++it) {
      int idx = it * 256 + tid;
      int row = idx >> 3, kc = (idx & 7) << 3;
      uint4 v = *(const uint4*)(Bt + (size_t)(n0 + row) * DM + k0 + kc);
      *(uint4*)(Bs + row * 72 + kc) = v;
    }
    __syncthreads();
    #pragma unroll
    for (int ks = 0; ks < 2; ++ks) {
      bf16x8 a[4], b[4];
      #pragma unroll
      for (int mi = 0; mi < 4; ++mi)
        a[mi] = *(const bf16x8*)(As + (wm * 64 + mi * 16 + l16) * 72 + ks * 32 + quad * 8);
      #pragma unroll
      for (int ni = 0; ni < 4; ++ni)
        b[ni] = *(const bf16x8*)(Bs + (wn * 64 + ni * 16 + l16) * 72 + ks * 32 + quad * 8);
      #pragma unroll
      for (int mi = 0; mi < 4; ++mi)
        #pragma unroll
        for (int ni = 0; ni < 4; ++ni)
          acc[mi][ni] = __builtin_amdgcn_mfma_f32_16x16x32_bf16(a[mi], b[ni], acc[mi][ni], 0, 0, 0);
    }
    __syncthreads();
  }

  // epilogue: + b1, exact gelu, bf16 store
  #pragma unroll
  for (int ni = 0; ni < 4; ++ni) {
    int col = n0 + wn * 64 + ni * 16 + l16;
    float bv = b1[e * NH + col];
    #pragma unroll
    for (int mi = 0; mi < 4; ++mi) {
      int rbase = wm * 64 + mi * 16 + quad * 4;
      #pragma unroll
      for (int r = 0; r < 4; ++r) {
        int grow = row0 + rbase + r;
        if (grow < row_end) {
          float v = acc[mi][ni][r] + bv;
          float gl = 0.5f * v * (1.0f + erff(v * 0.70710678118654752440f));
          hbuf[(size_t)grow * NH + col] = f2bf(gl);
        }
      }
    }
  }
}

// ---------------- layer 2: out[token] = (h @ w2t[e]^T + b2[e]) * w_token, scatter ----------------
__global__ __launch_bounds__(256) void k_ffn2(
    const uint16_t* __restrict__ hbuf, const uint16_t* __restrict__ w2t,
    const float* __restrict__ b2,
    const int* __restrict__ offsets, const int* __restrict__ counts,
    const int* __restrict__ perm, const float* __restrict__ wtok,
    float* __restrict__ out)
{
  int e = blockIdx.z;
  int row0 = offsets[e] + blockIdx.x * 128;
  int row_end = offsets[e] + counts[e];
  if (row0 >= row_end) return;
  int n0 = blockIdx.y * 128;
  const uint16_t* Bt = w2t + (size_t)e * NH * DM;   // [512][2048] bf16

  __shared__ uint16_t As[128 * 72];
  __shared__ uint16_t Bs[128 * 72];

  int tid = threadIdx.x;
  int lane = tid & 63, wid = tid >> 6;
  int wm = wid >> 1, wn = wid & 1;
  int l16 = lane & 15, quad = lane >> 4;

  f32x4 acc[4][4] = {};

  for (int k0 = 0; k0 < NH; k0 += 64) {
    #pragma unroll
    for (int it = 0; it < 4; ++it) {
      int idx = it * 256 + tid;
      int row = idx >> 3, kc = (idx & 7) << 3;
      uint4 v = *(const uint4*)(hbuf + (size_t)(row0 + row) * NH + k0 + kc);
      *(uint4*)(As + row * 72 + kc) = v;
    }
    #pragma unroll
    for (int it = 0; it < 4; ++it) {
      int idx = it * 256 + tid;
      int row = idx >> 3, kc = (idx & 7) << 3;
      uint4 v = *(const uint4*)(Bt + (size_t)(n0 + row) * NH + k0 + kc);
      *(uint4*)(Bs + row * 72 + kc) = v;
    }
    __syncthreads();
    #pragma unroll
    for (int ks = 0; ks < 2; ++ks) {
      bf16x8 a[4], b[4];
      #pragma unroll
      for (int mi = 0; mi < 4; ++mi)
        a[mi] = *(const bf16x8*)(As + (wm * 64 + mi * 16 + l16) * 72 + ks * 32 + quad * 8);
      #pragma unroll
      for (int ni = 0; ni < 4; ++ni)
        b[ni] = *(const bf16x8*)(Bs + (wn * 64 + ni * 16 + l16) * 72 + ks * 32 + quad * 8);
      #pragma unroll
      for (int mi = 0; mi < 4; ++mi)
        #pragma unroll
        for (int ni = 0; ni < 4; ++ni)
          acc[mi][ni] = __builtin_amdgcn_mfma_f32_16x16x32_bf16(a[mi], b[ni], acc[mi][ni], 0, 0, 0);
    }
    __syncthreads();
  }

  #pragma unroll
  for (int ni = 0; ni < 4; ++ni) {
    int col = n0 + wn * 64 + ni * 16 + l16;
    float bv = b2[e * DM + col];
    #pragma unroll
    for (int mi = 0; mi < 4; ++mi) {
      int rbase = wm * 64 + mi * 16 + quad * 4;
      #pragma unroll
      for (int r = 0; r < 4; ++r) {
        int grow = row0 + rbase + r;
        if (grow < row_end) {
          int tk = perm[grow];
          float wt = wtok[tk];
          out[(size_t)tk * DM + col] = (acc[mi][ni][r] + bv) * wt;
        }
      }
    }
  }
}

extern "C" void kernel_launch(void* const* d_in, const int* in_sizes, int n_in,
                              void* d_out, int out_size, void* d_ws, size_t ws_size,
                              hipStream_t stream)
{
  const float* x  = (const float*)d_in[0];
  const float* u  = (const float*)d_in[1];
  const float* rw = (const float*)d_in[2];
  const float* rb = (const float*)d_in[3];
  const float* w1 = (const float*)d_in[4];
  const float* b1 = (const float*)d_in[5];
  const float* w2 = (const float*)d_in[6];
  const float* b2 = (const float*)d_in[7];
  float* out = (float*)d_out;

  char* ws = (char*)d_ws;
  int*      counts    = (int*)(ws + WS_COUNTS);
  int*      cursors   = (int*)(ws + WS_CURSORS);
  int*      offsets   = (int*)(ws + WS_OFFSETS);
  float*    imp       = (float*)(ws + WS_IMP);
  int*      expert_of = (int*)(ws + WS_EXP);
  float*    wtok      = (float*)(ws + WS_WTOK);
  int*      perm      = (int*)(ws + WS_PERM);
  uint16_t* Xg        = (uint16_t*)(ws + WS_XG);
  uint16_t* hbuf      = (uint16_t*)(ws + WS_H);
  uint16_t* w1t       = (uint16_t*)(ws + WS_W1T);
  uint16_t* w2t       = (uint16_t*)(ws + WS_W2T);

  hipMemsetAsync(d_ws, 0, 128, stream);
  k_transpose_bf16<<<dim3(NH / 64, DM / 64, NE), 256, 0, stream>>>(w1, w1t, DM, NH);
  k_transpose_bf16<<<dim3(DM / 64, NH / 64, NE), 256, 0, stream>>>(w2, w2t, NH, DM);
  k_router<<<NUM_TOK / 256, 256, 0, stream>>>(x, u, rw, rb, counts, imp, expert_of, wtok);
  k_aux_offsets<<<1, 64, 0, stream>>>(counts, imp, offsets, out + (size_t)NUM_TOK * DM);
  k_scatter<<<NUM_TOK / 256, 256, 0, stream>>>(expert_of, offsets, cursors, perm);
  k_gather<<<NUM_TOK, 64, 0, stream>>>(x, perm, Xg);
  k_ffn1<<<dim3(64, 16, NE), 256, 0, stream>>>(Xg, w1t, b1, offsets, counts, hbuf);
  k_ffn2<<<dim3(64, 4, NE), 256, 0, stream>>>(hbuf, w2t, b2, offsets, counts, perm, wtok, out);
}